// Round 2
// baseline (931.722 us; speedup 1.0000x reference)
//
#include <hip/hip_runtime.h>

typedef _Float16 f16;
typedef _Float16 f16x8 __attribute__((ext_vector_type(8)));
typedef _Float16 f16x4 __attribute__((ext_vector_type(4)));
typedef float    f32x4 __attribute__((ext_vector_type(4)));

#define NB 4
#define SEQ 4096
#define DIM 512
#define MTOT (NB*SEQ)   // 16384

// async global->LDS, 16B per lane. lds dst must be wave-uniform base.
__device__ __forceinline__ void dma16(const f16* g, f16* l) {
    __builtin_amdgcn_global_load_lds(
        (const __attribute__((address_space(1))) unsigned int*)g,
        (__attribute__((address_space(3))) unsigned int*)l, 16, 0, 0);
}

// ---------------------------------------------------------------------------
// Projection GEMM: out[m,n] = f16( sum_k A[m,k] * W[n,k] + bias[n] )
// p: 0:q(x,Wq) natural  1:qv(x,Wqv) natural  2:k(y,Wk) K-swizzled
//    3:kv(y,Wkv) V-swizzled (transposed+swizzled for PV B-frags)
// Swizzled layouts (per batch, per 32-row kv tile t, per 256-D chunk):
//  K: unit = chunk*1024 + n*32 + ((ksl*4+q+n)&31), elem j ; d=chunk*256+ksl*32+q*8+j, n=s&31
//  V: unit = chunk*1024 + dl*4 + ((q+(dl>>1))&3), elem j  ; s=t*32+q*8+j, dl=d&255
// ---------------------------------------------------------------------------
__global__ __launch_bounds__(256) void proj_gemm(
    const float* __restrict__ x, const float* __restrict__ y,
    const float* __restrict__ Wq, const float* __restrict__ bq,
    const float* __restrict__ Wqv, const float* __restrict__ bqv,
    const float* __restrict__ Wk, const float* __restrict__ bk,
    const float* __restrict__ Wkv, const float* __restrict__ bkv,
    f16* __restrict__ qh, f16* __restrict__ qvh,
    f16* __restrict__ kS, f16* __restrict__ vS)
{
    __shared__ __attribute__((aligned(16))) f16 a_lds[128][40];
    __shared__ __attribute__((aligned(16))) f16 b_lds[128][40];

    const int p = blockIdx.z;
    const float* A    = (p < 2) ? x : y;
    const float* W    = (p==0)?Wq:(p==1)?Wqv:(p==2)?Wk:Wkv;
    const float* bias = (p==0)?bq:(p==1)?bqv:(p==2)?bk:bkv;

    const int m0 = blockIdx.y * 128, n0 = blockIdx.x * 128;
    const int tid = threadIdx.x, lane = tid & 63, wv = tid >> 6;
    const int wm = wv >> 1, wn = wv & 1, mrow = lane & 15, qd = lane >> 4;

    f32x4 acc[4][4];
#pragma unroll
    for (int mt = 0; mt < 4; ++mt)
#pragma unroll
        for (int nt = 0; nt < 4; ++nt) acc[mt][nt] = (f32x4){0.f,0.f,0.f,0.f};

    float bv[4];
#pragma unroll
    for (int nt = 0; nt < 4; ++nt) bv[nt] = bias[n0 + wn*64 + nt*16 + mrow];

    for (int k0 = 0; k0 < DIM; k0 += 32) {
        __syncthreads();
#pragma unroll
        for (int i = 0; i < 4; ++i) {
            int c = i*256 + tid;
            int row = c >> 3, c4 = c & 7;
            float4 v = *(const float4*)(A + (size_t)(m0+row)*DIM + k0 + c4*4);
            f16x4 h = { (f16)v.x, (f16)v.y, (f16)v.z, (f16)v.w };
            *(f16x4*)&a_lds[row][c4*4] = h;
        }
#pragma unroll
        for (int i = 0; i < 4; ++i) {
            int c = i*256 + tid;
            int row = c >> 3, c4 = c & 7;
            float4 v = *(const float4*)(W + (size_t)(n0+row)*DIM + k0 + c4*4);
            f16x4 h = { (f16)v.x, (f16)v.y, (f16)v.z, (f16)v.w };
            *(f16x4*)&b_lds[row][c4*4] = h;
        }
        __syncthreads();
        f16x8 af[4], bfr[4];
#pragma unroll
        for (int mt = 0; mt < 4; ++mt) af[mt]  = *(const f16x8*)&a_lds[wm*64 + mt*16 + mrow][qd*8];
#pragma unroll
        for (int nt = 0; nt < 4; ++nt) bfr[nt] = *(const f16x8*)&b_lds[wn*64 + nt*16 + mrow][qd*8];
#pragma unroll
        for (int mt = 0; mt < 4; ++mt)
#pragma unroll
            for (int nt = 0; nt < 4; ++nt)
                acc[mt][nt] = __builtin_amdgcn_mfma_f32_16x16x32_f16(af[mt], bfr[nt], acc[mt][nt], 0,0,0);
    }

    // epilogue: C layout col=lane&15, row=4*(lane>>4)+reg
#pragma unroll
    for (int mt = 0; mt < 4; ++mt)
#pragma unroll
        for (int r = 0; r < 4; ++r) {
            int g = m0 + wm*64 + mt*16 + qd*4 + r;           // token row
#pragma unroll
            for (int nt = 0; nt < 4; ++nt) {
                int d = n0 + wn*64 + nt*16 + mrow;            // out feature
                f16 val = (f16)(acc[mt][nt][r] + bv[nt]);
                if (p == 0) {
                    qh[(size_t)g*DIM + d] = val;
                } else if (p == 1) {
                    qvh[(size_t)g*DIM + d] = val;
                } else if (p == 2) {
                    int b = g >> 12, s = g & 4095;
                    int t = s >> 5, n = s & 31;
                    int chunk = d >> 8, ksl = (d >> 5) & 7, q = (d >> 3) & 3, j = d & 7;
                    size_t idx = (((size_t)((b*128 + t)*2048 + chunk*1024
                                   + n*32 + ((ksl*4 + q + n) & 31))) << 3) + j;
                    kS[idx] = val;
                } else {
                    int b = g >> 12, s = g & 4095;
                    int t = s >> 5, q = (s >> 3) & 3, j = s & 7;
                    int chunk = d >> 8, dl = d & 255;
                    size_t idx = (((size_t)((b*128 + t)*2048 + chunk*1024
                                   + dl*4 + ((q + (dl >> 1)) & 3))) << 3) + j;
                    vS[idx] = val;
                }
            }
        }
}

// ---------------------------------------------------------------------------
// Flash attention, pipelined: per wg (128 thr, 2 waves) one 32-row Q tile.
// kv-tile 32, staged as 4 chunks of 16KB (K d0-255, K d256-511, V d0-255,
// V d256-511) through a 3-buffer LDS ring via global_load_lds; prefetch
// depth 2 chunks; raw s_barrier + s_waitcnt vmcnt(8) (never 0).
// ---------------------------------------------------------------------------
__global__ __launch_bounds__(128, 2) void attn_kernel(
    const f16* __restrict__ qh, const f16* __restrict__ kS,
    const f16* __restrict__ vS, const f16* __restrict__ qvh,
    f16* __restrict__ ao)
{
    __shared__ __attribute__((aligned(16))) f16 ring[3][8192];   // 3 x 16KB
    __shared__ __attribute__((aligned(16))) f16 p_lds[2][16][40];

    const int bx = blockIdx.x;
    const int b  = bx >> 7;
    const int qt = bx & 127;
    const int tid = threadIdx.x, lane = tid & 63, w = tid >> 6;
    const int mrow = lane & 15, qd = lane >> 4;

    const f16* kSb = kS + ((size_t)b << 21);   // b*128 tiles *2048 units *8
    const f16* vSb = vS + ((size_t)b << 21);

    // Q fragments (A-layout): lane m+16q holds Q[m][32*ks + 8q + j]
    const size_t qrow = (size_t)(b*SEQ + qt*32 + w*16 + mrow) * DIM;
    f16x8 qf[16];
#pragma unroll
    for (int ks = 0; ks < 16; ++ks)
        qf[ks] = *(const f16x8*)(qh + qrow + ks*32 + qd*8);

    // prologue: chunks 0,1 in flight
    {
#pragma unroll
        for (int cc = 0; cc < 2; ++cc) {
            const f16* g = kSb + ((size_t)(cc & 1) << 13);   // tile0, K chunk cc
            f16* dst = &ring[cc][0];
#pragma unroll
            for (int o = 0; o < 8; ++o) {
                int ub = (o*2 + w) << 6;
                dma16(g + ((size_t)(ub + lane) << 3), dst + ((size_t)ub << 3));
            }
        }
    }

    f32x4 o[32];
#pragma unroll
    for (int nt = 0; nt < 32; ++nt) o[nt] = (f32x4){0.f,0.f,0.f,0.f};
    f32x4 o_l = (f32x4){0.f,0.f,0.f,0.f};
    float m_i[4] = {-INFINITY,-INFINITY,-INFINITY,-INFINITY};
    const f16x8 ones = {(f16)1.f,(f16)1.f,(f16)1.f,(f16)1.f,
                        (f16)1.f,(f16)1.f,(f16)1.f,(f16)1.f};

    for (int i = 0; i < 128; ++i) {
        const int c0 = i * 4;
        f32x4 s0 = (f32x4){0.f,0.f,0.f,0.f}, s1 = s0;

        // ---- phases 0,1: K halves -> S accumulation ----
#pragma unroll
        for (int ph = 0; ph < 2; ++ph) {
            __asm__ __volatile__("" ::: "memory");
            __builtin_amdgcn_s_waitcnt(0x0F78);   // vmcnt(8): this chunk done
            __builtin_amdgcn_s_barrier();
            __asm__ __volatile__("" ::: "memory");
            {   // issue chunk c0+ph+2 into its ring slot
                int cc = c0 + ph + 2; if (cc > 511) cc = 511;
                int t = cc >> 2, php = cc & 3;
                const f16* g = ((php < 2) ? kSb : vSb)
                             + (((size_t)t*2048 + (size_t)(php & 1)*1024) << 3);
                f16* dst = &ring[(c0 + ph + 2) % 3][0];
#pragma unroll
                for (int oo = 0; oo < 8; ++oo) {
                    int ub = (oo*2 + w) << 6;
                    dma16(g + ((size_t)(ub + lane) << 3), dst + ((size_t)ub << 3));
                }
            }
            const f16* kb = &ring[(c0 + ph) % 3][0];
#pragma unroll
            for (int ksl = 0; ksl < 8; ++ksl) {
                int n0a = mrow, n1a = 16 + mrow;
                f16x8 kf0 = *(const f16x8*)(kb + ((n0a*32 + ((ksl*4 + qd + n0a) & 31)) << 3));
                f16x8 kf1 = *(const f16x8*)(kb + ((n1a*32 + ((ksl*4 + qd + n1a) & 31)) << 3));
                s0 = __builtin_amdgcn_mfma_f32_16x16x32_f16(qf[ph*8 + ksl], kf0, s0, 0,0,0);
                s1 = __builtin_amdgcn_mfma_f32_16x16x32_f16(qf[ph*8 + ksl], kf1, s1, 0,0,0);
            }
        }

        // ---- online softmax (row r = 4*qd+rr over quad's 16 lanes) ----
        float alpha[4];
        bool changed = false;
#pragma unroll
        for (int rr = 0; rr < 4; ++rr) {
            float v = fmaxf(s0[rr], s1[rr]);
            v = fmaxf(v, __shfl_xor(v, 1));
            v = fmaxf(v, __shfl_xor(v, 2));
            v = fmaxf(v, __shfl_xor(v, 4));
            v = fmaxf(v, __shfl_xor(v, 8));
            float mn = fmaxf(m_i[rr], v);
            alpha[rr] = __expf(m_i[rr] - mn);
            if (mn > m_i[rr]) changed = true;
            m_i[rr] = mn;
            s0[rr] = __expf(s0[rr] - mn);
            s1[rr] = __expf(s1[rr] - mn);
        }
        if (__any(changed)) {
#pragma unroll
            for (int nt = 0; nt < 32; ++nt)
#pragma unroll
                for (int rr = 0; rr < 4; ++rr) o[nt][rr] *= alpha[rr];
#pragma unroll
            for (int rr = 0; rr < 4; ++rr) o_l[rr] *= alpha[rr];
        }

        // P: C-layout -> A-layout via per-wave LDS
#pragma unroll
        for (int rr = 0; rr < 4; ++rr) {
            p_lds[w][qd*4 + rr][mrow]      = (f16)s0[rr];
            p_lds[w][qd*4 + rr][16 + mrow] = (f16)s1[rr];
        }
        f16x8 pf = *(const f16x8*)&p_lds[w][mrow][qd*8];
        o_l = __builtin_amdgcn_mfma_f32_16x16x32_f16(pf, ones, o_l, 0,0,0);  // l += rowsum(P)

        // ---- phases 2,3: V halves -> O accumulation ----
#pragma unroll
        for (int ph = 2; ph < 4; ++ph) {
            __asm__ __volatile__("" ::: "memory");
            __builtin_amdgcn_s_waitcnt(0x0F78);
            __builtin_amdgcn_s_barrier();
            __asm__ __volatile__("" ::: "memory");
            {
                int cc = c0 + ph + 2; if (cc > 511) cc = 511;
                int t = cc >> 2, php = cc & 3;
                const f16* g = ((php < 2) ? kSb : vSb)
                             + (((size_t)t*2048 + (size_t)(php & 1)*1024) << 3);
                f16* dst = &ring[(c0 + ph + 2) % 3][0];
#pragma unroll
                for (int oo = 0; oo < 8; ++oo) {
                    int ub = (oo*2 + w) << 6;
                    dma16(g + ((size_t)(ub + lane) << 3), dst + ((size_t)ub << 3));
                }
            }
            const f16* vb = &ring[(c0 + ph) % 3][0];
#pragma unroll
            for (int ntl = 0; ntl < 16; ++ntl) {
                int nt = (ph - 2)*16 + ntl;
                int dl = ntl*16 + mrow;
                f16x8 vf = *(const f16x8*)(vb + ((dl*4 + ((qd + (dl >> 1)) & 3)) << 3));
                o[nt] = __builtin_amdgcn_mfma_f32_16x16x32_f16(pf, vf, o[nt], 0,0,0);
            }
        }
    }

    __builtin_amdgcn_s_waitcnt(0x0F70);   // vmcnt(0): drain tail DMAs

    // epilogue: O/l + qv
    float inv_l[4];
#pragma unroll
    for (int rr = 0; rr < 4; ++rr) inv_l[rr] = 1.f / o_l[rr];
#pragma unroll
    for (int rr = 0; rr < 4; ++rr) {
        size_t grow = (size_t)(b*SEQ + qt*32 + w*16 + qd*4 + rr) * DIM;
#pragma unroll
        for (int nt = 0; nt < 32; ++nt) {
            int col = nt*16 + mrow;
            float val = o[nt][rr] * inv_l[rr] + (float)qvh[grow + col];
            ao[grow + col] = (f16)val;
        }
    }
}

// ---------------------------------------------------------------------------
// Final linear: out[m,n] = sum_k ao[m,k]*Wf[n,k] + bf[n]  (f32 out)
// ---------------------------------------------------------------------------
__global__ __launch_bounds__(256) void final_gemm(
    const f16* __restrict__ ao, const float* __restrict__ Wf,
    const float* __restrict__ bf, float* __restrict__ out)
{
    __shared__ __attribute__((aligned(16))) f16 a_lds[128][40];
    __shared__ __attribute__((aligned(16))) f16 b_lds[128][40];

    const int m0 = blockIdx.y * 128, n0 = blockIdx.x * 128;
    const int tid = threadIdx.x, lane = tid & 63, wv = tid >> 6;
    const int wm = wv >> 1, wn = wv & 1, mrow = lane & 15, qd = lane >> 4;

    f32x4 acc[4][4];
#pragma unroll
    for (int mt = 0; mt < 4; ++mt)
#pragma unroll
        for (int nt = 0; nt < 4; ++nt) acc[mt][nt] = (f32x4){0.f,0.f,0.f,0.f};

    float bv[4];
#pragma unroll
    for (int nt = 0; nt < 4; ++nt) bv[nt] = bf[n0 + wn*64 + nt*16 + mrow];

    for (int k0 = 0; k0 < DIM; k0 += 32) {
        __syncthreads();
#pragma unroll
        for (int i = 0; i < 2; ++i) {
            int c = i*256 + tid;
            int row = c >> 2, c8 = c & 3;
            *(f16x8*)&a_lds[row][c8*8] =
                *(const f16x8*)(ao + (size_t)(m0+row)*DIM + k0 + c8*8);
        }
#pragma unroll
        for (int i = 0; i < 4; ++i) {
            int c = i*256 + tid;
            int row = c >> 3, c4 = c & 7;
            float4 v = *(const float4*)(Wf + (size_t)(n0+row)*DIM + k0 + c4*4);
            f16x4 h = { (f16)v.x, (f16)v.y, (f16)v.z, (f16)v.w };
            *(f16x4*)&b_lds[row][c4*4] = h;
        }
        __syncthreads();
        f16x8 af[4], bfr[4];
#pragma unroll
        for (int mt = 0; mt < 4; ++mt) af[mt]  = *(const f16x8*)&a_lds[wm*64 + mt*16 + mrow][qd*8];
#pragma unroll
        for (int nt = 0; nt < 4; ++nt) bfr[nt] = *(const f16x8*)&b_lds[wn*64 + nt*16 + mrow][qd*8];
#pragma unroll
        for (int mt = 0; mt < 4; ++mt)
#pragma unroll
            for (int nt = 0; nt < 4; ++nt)
                acc[mt][nt] = __builtin_amdgcn_mfma_f32_16x16x32_f16(af[mt], bfr[nt], acc[mt][nt], 0,0,0);
    }
#pragma unroll
    for (int mt = 0; mt < 4; ++mt)
#pragma unroll
        for (int r = 0; r < 4; ++r) {
            size_t grow = (size_t)(m0 + wm*64 + mt*16 + qd*4 + r) * DIM;
#pragma unroll
            for (int nt = 0; nt < 4; ++nt) {
                int col = n0 + wn*64 + nt*16 + mrow;
                out[grow + col] = acc[mt][nt][r] + bv[nt];
            }
        }
}

// ---------------------------------------------------------------------------
extern "C" void kernel_launch(void* const* d_in, const int* in_sizes, int n_in,
                              void* d_out, int out_size, void* d_ws, size_t ws_size,
                              hipStream_t stream)
{
    const float* x   = (const float*)d_in[0];
    const float* y   = (const float*)d_in[1];
    const float* Wq  = (const float*)d_in[2];
    const float* bq  = (const float*)d_in[3];
    const float* Wqv = (const float*)d_in[4];
    const float* bqv = (const float*)d_in[5];
    const float* Wk  = (const float*)d_in[6];
    const float* bk  = (const float*)d_in[7];
    const float* Wkv = (const float*)d_in[8];
    const float* bkv = (const float*)d_in[9];
    const float* Wf  = (const float*)d_in[10];
    const float* bf  = (const float*)d_in[11];
    float* out = (float*)d_out;

    const size_t NE = (size_t)MTOT * DIM;
    f16* qh  = (f16*)d_ws;       // 16.8 MB each; 84 MB total
    f16* qvh = qh  + NE;
    f16* kS  = qvh + NE;
    f16* vS  = kS  + NE;
    f16* aob = vS  + NE;

    proj_gemm<<<dim3(4, 128, 4), 256, 0, stream>>>(
        x, y, Wq, bq, Wqv, bqv, Wk, bk, Wkv, bkv, qh, qvh, kS, vS);
    attn_kernel<<<dim3(512), 128, 0, stream>>>(qh, kS, vS, qvh, aob);
    final_gemm<<<dim3(4, 128), 256, 0, stream>>>(aob, Wf, bf, out);
}

// Round 3
// 689.977 us; speedup vs baseline: 1.3504x; 1.3504x over previous
//
#include <hip/hip_runtime.h>

typedef _Float16 f16;
typedef _Float16 f16x8 __attribute__((ext_vector_type(8)));
typedef _Float16 f16x4 __attribute__((ext_vector_type(4)));
typedef float    f32x4 __attribute__((ext_vector_type(4)));

#define NB 4
#define SEQ 4096
#define DIM 512
#define MTOT (NB*SEQ)   // 16384
#define NEL ((size_t)MTOT*DIM)

// ---------------------------------------------------------------------------
// Projection GEMM: out[m,n] = f16( sum_k A[m,k] * W[n,k] + bias[n] )
// p: 0:q natural  1:qv natural  2:k K-swizzled  3:kv V-swizzled
// Swizzled layouts (per batch, per 32-row kv tile t, per 256-D chunk), unit=8 f16:
//  K: unit = t*2048 + chunk*1024 + n*32 + ((ksl*4+q+n)&31), elem j
//     where d = chunk*256 + ksl*32 + q*8 + j, n = s&31
//  V: unit = t*2048 + chunk*1024 + dl*4 + ((q+(dl>>1))&3), elem j
//     where s = t*32 + q*8 + j, dl = d&255
// ---------------------------------------------------------------------------
__global__ __launch_bounds__(256) void proj_gemm(
    const float* __restrict__ x, const float* __restrict__ y,
    const float* __restrict__ Wq, const float* __restrict__ bq,
    const float* __restrict__ Wqv, const float* __restrict__ bqv,
    const float* __restrict__ Wk, const float* __restrict__ bk,
    const float* __restrict__ Wkv, const float* __restrict__ bkv,
    f16* __restrict__ qh, f16* __restrict__ qvh,
    f16* __restrict__ kS, f16* __restrict__ vS)
{
    __shared__ __attribute__((aligned(16))) f16 a_lds[128][40];
    __shared__ __attribute__((aligned(16))) f16 b_lds[128][40];

    const int p = blockIdx.z;
    const float* A    = (p < 2) ? x : y;
    const float* W    = (p==0)?Wq:(p==1)?Wqv:(p==2)?Wk:Wkv;
    const float* bias = (p==0)?bq:(p==1)?bqv:(p==2)?bk:bkv;

    const int m0 = blockIdx.y * 128, n0 = blockIdx.x * 128;
    const int tid = threadIdx.x, lane = tid & 63, wv = tid >> 6;
    const int wm = wv >> 1, wn = wv & 1, mrow = lane & 15, qd = lane >> 4;

    f32x4 acc[4][4];
#pragma unroll
    for (int mt = 0; mt < 4; ++mt)
#pragma unroll
        for (int nt = 0; nt < 4; ++nt) acc[mt][nt] = (f32x4){0.f,0.f,0.f,0.f};

    float bv[4];
#pragma unroll
    for (int nt = 0; nt < 4; ++nt) bv[nt] = bias[n0 + wn*64 + nt*16 + mrow];

    for (int k0 = 0; k0 < DIM; k0 += 32) {
        __syncthreads();
#pragma unroll
        for (int i = 0; i < 4; ++i) {
            int c = i*256 + tid;
            int row = c >> 3, c4 = c & 7;
            float4 v = *(const float4*)(A + (size_t)(m0+row)*DIM + k0 + c4*4);
            f16x4 hh = { (f16)v.x, (f16)v.y, (f16)v.z, (f16)v.w };
            *(f16x4*)&a_lds[row][c4*4] = hh;
        }
#pragma unroll
        for (int i = 0; i < 4; ++i) {
            int c = i*256 + tid;
            int row = c >> 3, c4 = c & 7;
            float4 v = *(const float4*)(W + (size_t)(n0+row)*DIM + k0 + c4*4);
            f16x4 hh = { (f16)v.x, (f16)v.y, (f16)v.z, (f16)v.w };
            *(f16x4*)&b_lds[row][c4*4] = hh;
        }
        __syncthreads();
        f16x8 af[4], bfr[4];
#pragma unroll
        for (int mt = 0; mt < 4; ++mt) af[mt]  = *(const f16x8*)&a_lds[wm*64 + mt*16 + mrow][qd*8];
#pragma unroll
        for (int nt = 0; nt < 4; ++nt) bfr[nt] = *(const f16x8*)&b_lds[wn*64 + nt*16 + mrow][qd*8];
#pragma unroll
        for (int mt = 0; mt < 4; ++mt)
#pragma unroll
            for (int nt = 0; nt < 4; ++nt)
                acc[mt][nt] = __builtin_amdgcn_mfma_f32_16x16x32_f16(af[mt], bfr[nt], acc[mt][nt], 0,0,0);
    }

#pragma unroll
    for (int mt = 0; mt < 4; ++mt)
#pragma unroll
        for (int r = 0; r < 4; ++r) {
            int g = m0 + wm*64 + mt*16 + qd*4 + r;
#pragma unroll
            for (int nt = 0; nt < 4; ++nt) {
                int d = n0 + wn*64 + nt*16 + mrow;
                f16 val = (f16)(acc[mt][nt][r] + bv[nt]);
                if (p == 0) {
                    qh[(size_t)g*DIM + d] = val;
                } else if (p == 1) {
                    qvh[(size_t)g*DIM + d] = val;
                } else if (p == 2) {
                    int b = g >> 12, s = g & 4095;
                    int t = s >> 5, n = s & 31;
                    int chunk = d >> 8, ksl = (d >> 5) & 7, q = (d >> 3) & 3, j = d & 7;
                    size_t idx = (((size_t)((b*128 + t)*2048 + chunk*1024
                                   + n*32 + ((ksl*4 + q + n) & 31))) << 3) + j;
                    kS[idx] = val;
                } else {
                    int b = g >> 12, s = g & 4095;
                    int t = s >> 5, q = (s >> 3) & 3, j = s & 7;
                    int chunk = d >> 8, dl = d & 255;
                    size_t idx = (((size_t)((b*128 + t)*2048 + chunk*1024
                                   + dl*4 + ((q + (dl >> 1)) & 3))) << 3) + j;
                    vS[idx] = val;
                }
            }
        }
}

// ---------------------------------------------------------------------------
// Flash attention, kv-split: block = 4 waves = 64 Q rows, one kv half (2048).
// 512 blocks -> 2 blocks/CU (LDS 69KB) -> 8 waves/CU.
// Per iter: stage one 32-row kv tile (K 32KB + V 32KB, swizzled, conflict-free)
// via regs; each wave computes S(16x32), online softmax, O += P@V.
// Partial normalized O + (m,l) per half written for the merge pass.
// ---------------------------------------------------------------------------
__global__ __launch_bounds__(256, 2) void attn_kernel(
    const f16* __restrict__ qh, const f16* __restrict__ kS,
    const f16* __restrict__ vS, f16* __restrict__ opart,
    float* __restrict__ ml)
{
    __shared__ __attribute__((aligned(16))) f16 k_lds[16384];   // 32KB
    __shared__ __attribute__((aligned(16))) f16 v_lds[16384];   // 32KB
    __shared__ __attribute__((aligned(16))) f16 p_lds[4][16][40];

    const int bx = blockIdx.x;
    const int h  = bx >> 8;          // kv half
    const int b  = (bx >> 6) & 3;    // batch
    const int qt = bx & 63;          // 64-row q tile
    const int tid = threadIdx.x, lane = tid & 63, w = tid >> 6;
    const int mrow = lane & 15, qd = lane >> 4;

    const f16* kSb = kS + ((size_t)b << 21) + ((size_t)h << 20);
    const f16* vSb = vS + ((size_t)b << 21) + ((size_t)h << 20);

    // Q fragments (A-layout): lane m+16q holds Q[m][32*ks + 8q + j]
    const size_t qrow = ((size_t)b*SEQ + qt*64 + w*16 + mrow) * DIM;
    f16x8 qf[16];
#pragma unroll
    for (int ks = 0; ks < 16; ++ks)
        qf[ks] = *(const f16x8*)(qh + qrow + ks*32 + qd*8);

    f32x4 o[32];
#pragma unroll
    for (int nt = 0; nt < 32; ++nt) o[nt] = (f32x4){0.f,0.f,0.f,0.f};
    f32x4 o_l = (f32x4){0.f,0.f,0.f,0.f};
    float m_i[4] = {-INFINITY,-INFINITY,-INFINITY,-INFINITY};
    const f16x8 ones = {(f16)1.f,(f16)1.f,(f16)1.f,(f16)1.f,
                        (f16)1.f,(f16)1.f,(f16)1.f,(f16)1.f};

    for (int i = 0; i < 64; ++i) {
        // issue staging loads BEFORE barrier: latency overlaps other waves' tails
        const f16* kt = kSb + (size_t)i*16384;
        const f16* vt = vSb + (size_t)i*16384;
        f16x8 sk[8], sv[8];
#pragma unroll
        for (int j = 0; j < 8; ++j) sk[j] = *(const f16x8*)(kt + (j*256 + tid)*8);
#pragma unroll
        for (int j = 0; j < 8; ++j) sv[j] = *(const f16x8*)(vt + (j*256 + tid)*8);
        __syncthreads();   // readers of tile i-1 done
#pragma unroll
        for (int j = 0; j < 8; ++j) *(f16x8*)&k_lds[(j*256 + tid)*8] = sk[j];
#pragma unroll
        for (int j = 0; j < 8; ++j) *(f16x8*)&v_lds[(j*256 + tid)*8] = sv[j];
        __syncthreads();

        // S = Q K^T : 16x32 per wave
        f32x4 s0 = (f32x4){0.f,0.f,0.f,0.f}, s1 = s0;
#pragma unroll
        for (int ks = 0; ks < 16; ++ks) {
            int chunk = ks >> 3, ksl = ks & 7;
            int n0a = mrow, n1a = 16 + mrow;
            f16x8 kf0 = *(const f16x8*)&k_lds[(chunk*1024 + n0a*32 + ((ksl*4 + qd + n0a) & 31)) << 3];
            f16x8 kf1 = *(const f16x8*)&k_lds[(chunk*1024 + n1a*32 + ((ksl*4 + qd + n1a) & 31)) << 3];
            s0 = __builtin_amdgcn_mfma_f32_16x16x32_f16(qf[ks], kf0, s0, 0,0,0);
            s1 = __builtin_amdgcn_mfma_f32_16x16x32_f16(qf[ks], kf1, s1, 0,0,0);
        }

        // online softmax (row r = 4*qd+rr across quad's 16 lanes)
        float alpha[4];
        bool changed = false;
#pragma unroll
        for (int rr = 0; rr < 4; ++rr) {
            float v = fmaxf(s0[rr], s1[rr]);
            v = fmaxf(v, __shfl_xor(v, 1));
            v = fmaxf(v, __shfl_xor(v, 2));
            v = fmaxf(v, __shfl_xor(v, 4));
            v = fmaxf(v, __shfl_xor(v, 8));
            float mn = fmaxf(m_i[rr], v);
            alpha[rr] = __expf(m_i[rr] - mn);
            if (mn > m_i[rr]) changed = true;
            m_i[rr] = mn;
            s0[rr] = __expf(s0[rr] - mn);
            s1[rr] = __expf(s1[rr] - mn);
        }
        if (__any(changed)) {
#pragma unroll
            for (int nt = 0; nt < 32; ++nt)
#pragma unroll
                for (int rr = 0; rr < 4; ++rr) o[nt][rr] *= alpha[rr];
#pragma unroll
            for (int rr = 0; rr < 4; ++rr) o_l[rr] *= alpha[rr];
        }

        // P: C-layout -> A-layout via per-wave LDS
#pragma unroll
        for (int rr = 0; rr < 4; ++rr) {
            p_lds[w][qd*4 + rr][mrow]      = (f16)s0[rr];
            p_lds[w][qd*4 + rr][16 + mrow] = (f16)s1[rr];
        }
        f16x8 pf = *(const f16x8*)&p_lds[w][mrow][qd*8];
        o_l = __builtin_amdgcn_mfma_f32_16x16x32_f16(pf, ones, o_l, 0,0,0);

        // O += P @ V : 32 d-tiles
#pragma unroll
        for (int nt = 0; nt < 32; ++nt) {
            int d = nt*16 + mrow;
            int chunk = d >> 8, dl = d & 255;
            f16x8 vf = *(const f16x8*)&v_lds[(chunk*1024 + dl*4 + ((qd + (dl >> 1)) & 3)) << 3];
            o[nt] = __builtin_amdgcn_mfma_f32_16x16x32_f16(pf, vf, o[nt], 0,0,0);
        }
    }

    // epilogue: normalized partial O + (m,l)
    float inv_l[4];
#pragma unroll
    for (int rr = 0; rr < 4; ++rr) inv_l[rr] = 1.f / o_l[rr];
#pragma unroll
    for (int rr = 0; rr < 4; ++rr) {
        size_t grow = ((size_t)b*SEQ + qt*64 + w*16 + qd*4 + rr) * DIM;
#pragma unroll
        for (int nt = 0; nt < 32; ++nt) {
            int col = nt*16 + mrow;
            opart[(size_t)h*NEL + grow + col] = (f16)(o[nt][rr] * inv_l[rr]);
        }
    }
    if (mrow == 0) {
#pragma unroll
        for (int rr = 0; rr < 4; ++rr) {
            int idx = (h << 14) + b*SEQ + qt*64 + w*16 + qd*4 + rr;
            ml[idx*2 + 0] = m_i[rr];
            ml[idx*2 + 1] = o_l[rr];
        }
    }
}

// ---------------------------------------------------------------------------
// Merge the two kv-half partials (LSE-weighted) + qv residual -> ao (f16)
// ---------------------------------------------------------------------------
__global__ __launch_bounds__(256) void merge_kernel(
    const f16* __restrict__ opart, const float* __restrict__ ml,
    const f16* __restrict__ qvh, f16* __restrict__ ao)
{
    int gid = blockIdx.x * 256 + threadIdx.x;
    int row = gid >> 6;
    int dc  = (gid & 63) * 8;
    float m1 = ml[row*2 + 0],           l1 = ml[row*2 + 1];
    float m2 = ml[(row + MTOT)*2 + 0],  l2 = ml[(row + MTOT)*2 + 1];
    float mm = fmaxf(m1, m2);
    float w1 = __expf(m1 - mm) * l1, w2 = __expf(m2 - mm) * l2;
    float il = 1.f / (w1 + w2);
    w1 *= il; w2 *= il;
    f16x8 o1 = *(const f16x8*)(opart + (size_t)row*DIM + dc);
    f16x8 o2 = *(const f16x8*)(opart + NEL + (size_t)row*DIM + dc);
    f16x8 qv = *(const f16x8*)(qvh + (size_t)row*DIM + dc);
    f16x8 r;
#pragma unroll
    for (int j = 0; j < 8; ++j)
        r[j] = (f16)(w1*(float)o1[j] + w2*(float)o2[j] + (float)qv[j]);
    *(f16x8*)(ao + (size_t)row*DIM + dc) = r;
}

// ---------------------------------------------------------------------------
// Final linear: out[m,n] = sum_k ao[m,k]*Wf[n,k] + bf[n]  (f32 out)
// ---------------------------------------------------------------------------
__global__ __launch_bounds__(256) void final_gemm(
    const f16* __restrict__ ao, const float* __restrict__ Wf,
    const float* __restrict__ bf, float* __restrict__ out)
{
    __shared__ __attribute__((aligned(16))) f16 a_lds[128][40];
    __shared__ __attribute__((aligned(16))) f16 b_lds[128][40];

    const int m0 = blockIdx.y * 128, n0 = blockIdx.x * 128;
    const int tid = threadIdx.x, lane = tid & 63, wv = tid >> 6;
    const int wm = wv >> 1, wn = wv & 1, mrow = lane & 15, qd = lane >> 4;

    f32x4 acc[4][4];
#pragma unroll
    for (int mt = 0; mt < 4; ++mt)
#pragma unroll
        for (int nt = 0; nt < 4; ++nt) acc[mt][nt] = (f32x4){0.f,0.f,0.f,0.f};

    float bv[4];
#pragma unroll
    for (int nt = 0; nt < 4; ++nt) bv[nt] = bf[n0 + wn*64 + nt*16 + mrow];

    for (int k0 = 0; k0 < DIM; k0 += 32) {
        __syncthreads();
#pragma unroll
        for (int i = 0; i < 2; ++i) {
            int c = i*256 + tid;
            int row = c >> 2, c8 = c & 3;
            *(f16x8*)&a_lds[row][c8*8] =
                *(const f16x8*)(ao + (size_t)(m0+row)*DIM + k0 + c8*8);
        }
#pragma unroll
        for (int i = 0; i < 4; ++i) {
            int c = i*256 + tid;
            int row = c >> 3, c4 = c & 7;
            float4 v = *(const float4*)(Wf + (size_t)(n0+row)*DIM + k0 + c4*4);
            f16x4 hh = { (f16)v.x, (f16)v.y, (f16)v.z, (f16)v.w };
            *(f16x4*)&b_lds[row][c4*4] = hh;
        }
        __syncthreads();
        f16x8 af[4], bfr[4];
#pragma unroll
        for (int mt = 0; mt < 4; ++mt) af[mt]  = *(const f16x8*)&a_lds[wm*64 + mt*16 + mrow][qd*8];
#pragma unroll
        for (int nt = 0; nt < 4; ++nt) bfr[nt] = *(const f16x8*)&b_lds[wn*64 + nt*16 + mrow][qd*8];
#pragma unroll
        for (int mt = 0; mt < 4; ++mt)
#pragma unroll
            for (int nt = 0; nt < 4; ++nt)
                acc[mt][nt] = __builtin_amdgcn_mfma_f32_16x16x32_f16(af[mt], bfr[nt], acc[mt][nt], 0,0,0);
    }
#pragma unroll
    for (int mt = 0; mt < 4; ++mt)
#pragma unroll
        for (int r = 0; r < 4; ++r) {
            size_t grow = (size_t)(m0 + wm*64 + mt*16 + qd*4 + r) * DIM;
#pragma unroll
            for (int nt = 0; nt < 4; ++nt) {
                int col = n0 + wn*64 + nt*16 + mrow;
                out[grow + col] = acc[mt][nt][r] + bv[nt];
            }
        }
}

// ---------------------------------------------------------------------------
extern "C" void kernel_launch(void* const* d_in, const int* in_sizes, int n_in,
                              void* d_out, int out_size, void* d_ws, size_t ws_size,
                              hipStream_t stream)
{
    const float* x   = (const float*)d_in[0];
    const float* y   = (const float*)d_in[1];
    const float* Wq  = (const float*)d_in[2];
    const float* bq  = (const float*)d_in[3];
    const float* Wqv = (const float*)d_in[4];
    const float* bqv = (const float*)d_in[5];
    const float* Wk  = (const float*)d_in[6];
    const float* bk  = (const float*)d_in[7];
    const float* Wkv = (const float*)d_in[8];
    const float* bkv = (const float*)d_in[9];
    const float* Wf  = (const float*)d_in[10];
    const float* bf  = (const float*)d_in[11];
    float* out = (float*)d_out;

    f16* qh    = (f16*)d_ws;       // NEL each (16.8MB); total ~101MB
    f16* qvh   = qh  + NEL;
    f16* kS    = qvh + NEL;
    f16* vS    = kS  + NEL;
    f16* opart = vS  + NEL;        // 2*NEL (two halves)
    float* ml  = (float*)(opart + 2*NEL);  // 2*16384*2 floats
    f16* aob   = kS;               // alias: kS dead after attn_kernel

    proj_gemm<<<dim3(4, 128, 4), 256, 0, stream>>>(
        x, y, Wq, bq, Wqv, bqv, Wk, bk, Wkv, bkv, qh, qvh, kS, vS);
    attn_kernel<<<dim3(512), 256, 0, stream>>>(qh, kS, vS, opart, ml);
    merge_kernel<<<dim3(4096), 256, 0, stream>>>(opart, ml, qvh, aob);
    final_gemm<<<dim3(4, 128), 256, 0, stream>>>(aob, Wf, bf, out);
}

// Round 4
// 548.616 us; speedup vs baseline: 1.6983x; 1.2577x over previous
//
#include <hip/hip_runtime.h>

typedef _Float16 f16;
typedef _Float16 f16x8 __attribute__((ext_vector_type(8)));
typedef _Float16 f16x4 __attribute__((ext_vector_type(4)));
typedef float    f32x4 __attribute__((ext_vector_type(4)));

#define NB 4
#define SEQ 4096
#define DIM 512
#define MTOT (NB*SEQ)   // 16384
#define NEL ((size_t)MTOT*DIM)

// ---------------------------------------------------------------------------
// Projection GEMM: out[m,n] = f16( sum_k A[m,k] * W[n,k] + bias[n] )
// p: 0:q natural  1:qv natural  2:k K-swizzled  3:kv V-swizzled
// Swizzled layouts (per batch, per 32-row kv tile t, per 256-D chunk), unit=8 f16:
//  K: unit = t*2048 + chunk*1024 + n*32 + ((ksl*4+q+n)&31), elem j
//     where d = chunk*256 + ksl*32 + q*8 + j, n = s&31
//  V: unit = t*2048 + chunk*1024 + dl*4 + ((q+(dl>>1))&3), elem j
//     where s = t*32 + q*8 + j, dl = d&255
// ---------------------------------------------------------------------------
__global__ __launch_bounds__(256) void proj_gemm(
    const float* __restrict__ x, const float* __restrict__ y,
    const float* __restrict__ Wq, const float* __restrict__ bq,
    const float* __restrict__ Wqv, const float* __restrict__ bqv,
    const float* __restrict__ Wk, const float* __restrict__ bk,
    const float* __restrict__ Wkv, const float* __restrict__ bkv,
    f16* __restrict__ qh, f16* __restrict__ qvh,
    f16* __restrict__ kS, f16* __restrict__ vS)
{
    __shared__ __attribute__((aligned(16))) f16 a_lds[128][40];
    __shared__ __attribute__((aligned(16))) f16 b_lds[128][40];

    const int p = blockIdx.z;
    const float* A    = (p < 2) ? x : y;
    const float* W    = (p==0)?Wq:(p==1)?Wqv:(p==2)?Wk:Wkv;
    const float* bias = (p==0)?bq:(p==1)?bqv:(p==2)?bk:bkv;

    const int m0 = blockIdx.y * 128, n0 = blockIdx.x * 128;
    const int tid = threadIdx.x, lane = tid & 63, wv = tid >> 6;
    const int wm = wv >> 1, wn = wv & 1, mrow = lane & 15, qd = lane >> 4;

    f32x4 acc[4][4];
#pragma unroll
    for (int mt = 0; mt < 4; ++mt)
#pragma unroll
        for (int nt = 0; nt < 4; ++nt) acc[mt][nt] = (f32x4){0.f,0.f,0.f,0.f};

    float bv[4];
#pragma unroll
    for (int nt = 0; nt < 4; ++nt) bv[nt] = bias[n0 + wn*64 + nt*16 + mrow];

    for (int k0 = 0; k0 < DIM; k0 += 32) {
        __syncthreads();
#pragma unroll
        for (int i = 0; i < 4; ++i) {
            int c = i*256 + tid;
            int row = c >> 3, c4 = c & 7;
            float4 v = *(const float4*)(A + (size_t)(m0+row)*DIM + k0 + c4*4);
            f16x4 hh = { (f16)v.x, (f16)v.y, (f16)v.z, (f16)v.w };
            *(f16x4*)&a_lds[row][c4*4] = hh;
        }
#pragma unroll
        for (int i = 0; i < 4; ++i) {
            int c = i*256 + tid;
            int row = c >> 3, c4 = c & 7;
            float4 v = *(const float4*)(W + (size_t)(n0+row)*DIM + k0 + c4*4);
            f16x4 hh = { (f16)v.x, (f16)v.y, (f16)v.z, (f16)v.w };
            *(f16x4*)&b_lds[row][c4*4] = hh;
        }
        __syncthreads();
        f16x8 af[4], bfr[4];
#pragma unroll
        for (int mt = 0; mt < 4; ++mt) af[mt]  = *(const f16x8*)&a_lds[wm*64 + mt*16 + mrow][qd*8];
#pragma unroll
        for (int nt = 0; nt < 4; ++nt) bfr[nt] = *(const f16x8*)&b_lds[wn*64 + nt*16 + mrow][qd*8];
#pragma unroll
        for (int mt = 0; mt < 4; ++mt)
#pragma unroll
            for (int nt = 0; nt < 4; ++nt)
                acc[mt][nt] = __builtin_amdgcn_mfma_f32_16x16x32_f16(af[mt], bfr[nt], acc[mt][nt], 0,0,0);
    }

#pragma unroll
    for (int mt = 0; mt < 4; ++mt)
#pragma unroll
        for (int r = 0; r < 4; ++r) {
            int g = m0 + wm*64 + mt*16 + qd*4 + r;
#pragma unroll
            for (int nt = 0; nt < 4; ++nt) {
                int d = n0 + wn*64 + nt*16 + mrow;
                f16 val = (f16)(acc[mt][nt][r] + bv[nt]);
                if (p == 0) {
                    qh[(size_t)g*DIM + d] = val;
                } else if (p == 1) {
                    qvh[(size_t)g*DIM + d] = val;
                } else if (p == 2) {
                    int b = g >> 12, s = g & 4095;
                    int t = s >> 5, n = s & 31;
                    int chunk = d >> 8, ksl = (d >> 5) & 7, q = (d >> 3) & 3, j = d & 7;
                    size_t idx = (((size_t)((b*128 + t)*2048 + chunk*1024
                                   + n*32 + ((ksl*4 + q + n) & 31))) << 3) + j;
                    kS[idx] = val;
                } else {
                    int b = g >> 12, s = g & 4095;
                    int t = s >> 5, q = (s >> 3) & 3, j = s & 7;
                    int chunk = d >> 8, dl = d & 255;
                    size_t idx = (((size_t)((b*128 + t)*2048 + chunk*1024
                                   + dl*4 + ((q + (dl >> 1)) & 3))) << 3) + j;
                    vS[idx] = val;
                }
            }
        }
}

// ---------------------------------------------------------------------------
// Flash attention: 256 blocks (1/CU), 4 waves, 64 Q rows, full KV sweep.
// XCD-swizzle: all 32 blocks on an XCD share one batch's KV (L2-resident
// tile in lockstep). Double-buffered K/V tiles (2 x 64KB LDS), register
// staging issued BEFORE compute, ONE barrier per iteration.
// ---------------------------------------------------------------------------
__global__ __launch_bounds__(256, 1) void attn_kernel(
    const f16* __restrict__ qh, const f16* __restrict__ kS,
    const f16* __restrict__ vS, const f16* __restrict__ qvh,
    f16* __restrict__ ao)
{
    __shared__ __attribute__((aligned(16))) f16 kbuf[2][16384];  // 2 x 32KB
    __shared__ __attribute__((aligned(16))) f16 vbuf[2][16384];  // 2 x 32KB
    __shared__ __attribute__((aligned(16))) f16 p_lds[4][16][40];

    const int xcd = blockIdx.x & 7;
    const int b   = xcd >> 1;                          // batch -> XCD pair
    const int qt  = (blockIdx.x >> 3) * 2 + (xcd & 1); // 0..63
    const int tid = threadIdx.x, lane = tid & 63, w = tid >> 6;
    const int mrow = lane & 15, qd = lane >> 4;

    const f16* kSb = kS + ((size_t)b << 21);
    const f16* vSb = vS + ((size_t)b << 21);

    // Q fragments (A-layout): lane m+16q holds Q[m][32*ks + 8q + j]
    const size_t qrow = ((size_t)b*SEQ + qt*64 + w*16 + mrow) * DIM;
    f16x8 qf[16];
#pragma unroll
    for (int ks = 0; ks < 16; ++ks)
        qf[ks] = *(const f16x8*)(qh + qrow + ks*32 + qd*8);

    f32x4 o[32];
#pragma unroll
    for (int nt = 0; nt < 32; ++nt) o[nt] = (f32x4){0.f,0.f,0.f,0.f};
    f32x4 o_l = (f32x4){0.f,0.f,0.f,0.f};
    float m_i[4] = {-INFINITY,-INFINITY,-INFINITY,-INFINITY};
    const f16x8 ones = {(f16)1.f,(f16)1.f,(f16)1.f,(f16)1.f,
                        (f16)1.f,(f16)1.f,(f16)1.f,(f16)1.f};

    f16x8 sk[8], sv[8];
    // prologue: stage tile 0 into buf 0
#pragma unroll
    for (int j = 0; j < 8; ++j) {
        sk[j] = *(const f16x8*)(kSb + (j*256 + tid)*8);
        sv[j] = *(const f16x8*)(vSb + (j*256 + tid)*8);
    }
#pragma unroll
    for (int j = 0; j < 8; ++j) {
        *(f16x8*)&kbuf[0][(j*256 + tid)*8] = sk[j];
        *(f16x8*)&vbuf[0][(j*256 + tid)*8] = sv[j];
    }
    __syncthreads();

    for (int i = 0; i < 128; ++i) {
        // issue next tile's loads NOW; vmcnt wait is ~2000 cyc later
        const int nxt = (i < 127) ? i + 1 : i;
        const f16* kt = kSb + (size_t)nxt*16384;
        const f16* vt = vSb + (size_t)nxt*16384;
#pragma unroll
        for (int j = 0; j < 8; ++j) {
            sk[j] = *(const f16x8*)(kt + (j*256 + tid)*8);
            sv[j] = *(const f16x8*)(vt + (j*256 + tid)*8);
        }

        const f16* kb = &kbuf[i & 1][0];
        const f16* vb = &vbuf[i & 1][0];

        // S = Q K^T : 16x32 per wave; 4 independent accumulation chains
        f32x4 s0a = (f32x4){0.f,0.f,0.f,0.f}, s0b = s0a, s1a = s0a, s1b = s0a;
#pragma unroll
        for (int ksl = 0; ksl < 8; ++ksl) {
            int n0a = mrow, n1a = 16 + mrow;
            f16x8 kf0 = *(const f16x8*)&kb[(n0a*32 + ((ksl*4 + qd + n0a) & 31)) << 3];
            f16x8 kf1 = *(const f16x8*)&kb[(n1a*32 + ((ksl*4 + qd + n1a) & 31)) << 3];
            f16x8 kg0 = *(const f16x8*)&kb[(1024 + n0a*32 + ((ksl*4 + qd + n0a) & 31)) << 3];
            f16x8 kg1 = *(const f16x8*)&kb[(1024 + n1a*32 + ((ksl*4 + qd + n1a) & 31)) << 3];
            s0a = __builtin_amdgcn_mfma_f32_16x16x32_f16(qf[ksl],     kf0, s0a, 0,0,0);
            s1a = __builtin_amdgcn_mfma_f32_16x16x32_f16(qf[ksl],     kf1, s1a, 0,0,0);
            s0b = __builtin_amdgcn_mfma_f32_16x16x32_f16(qf[8 + ksl], kg0, s0b, 0,0,0);
            s1b = __builtin_amdgcn_mfma_f32_16x16x32_f16(qf[8 + ksl], kg1, s1b, 0,0,0);
        }
        f32x4 s0, s1;
#pragma unroll
        for (int rr = 0; rr < 4; ++rr) { s0[rr] = s0a[rr] + s0b[rr]; s1[rr] = s1a[rr] + s1b[rr]; }

        // online softmax (row r = 4*qd+rr across quad's 16 lanes)
        float alpha[4];
        bool changed = false;
#pragma unroll
        for (int rr = 0; rr < 4; ++rr) {
            float v = fmaxf(s0[rr], s1[rr]);
            v = fmaxf(v, __shfl_xor(v, 1));
            v = fmaxf(v, __shfl_xor(v, 2));
            v = fmaxf(v, __shfl_xor(v, 4));
            v = fmaxf(v, __shfl_xor(v, 8));
            float mn = fmaxf(m_i[rr], v);
            alpha[rr] = __expf(m_i[rr] - mn);
            if (mn > m_i[rr]) changed = true;
            m_i[rr] = mn;
            s0[rr] = __expf(s0[rr] - mn);
            s1[rr] = __expf(s1[rr] - mn);
        }
        if (__any(changed)) {
#pragma unroll
            for (int nt = 0; nt < 32; ++nt)
#pragma unroll
                for (int rr = 0; rr < 4; ++rr) o[nt][rr] *= alpha[rr];
#pragma unroll
            for (int rr = 0; rr < 4; ++rr) o_l[rr] *= alpha[rr];
        }

        // P: C-layout -> A-layout via per-wave LDS
#pragma unroll
        for (int rr = 0; rr < 4; ++rr) {
            p_lds[w][qd*4 + rr][mrow]      = (f16)s0[rr];
            p_lds[w][qd*4 + rr][16 + mrow] = (f16)s1[rr];
        }
        f16x8 pf = *(const f16x8*)&p_lds[w][mrow][qd*8];
        o_l = __builtin_amdgcn_mfma_f32_16x16x32_f16(pf, ones, o_l, 0,0,0);

        // O += P @ V : 32 d-tiles
#pragma unroll
        for (int nt = 0; nt < 32; ++nt) {
            int d = nt*16 + mrow;
            int chunk = d >> 8, dl = d & 255;
            f16x8 vf = *(const f16x8*)&vb[(chunk*1024 + dl*4 + ((qd + (dl >> 1)) & 3)) << 3];
            o[nt] = __builtin_amdgcn_mfma_f32_16x16x32_f16(pf, vf, o[nt], 0,0,0);
        }

        // write next tile to the other buffer (its readers finished at the
        // barrier ending iter i-1); compiler inserts the vmcnt wait here.
        f16* kw = &kbuf[(i + 1) & 1][0];
        f16* vw = &vbuf[(i + 1) & 1][0];
#pragma unroll
        for (int j = 0; j < 8; ++j) {
            *(f16x8*)&kw[(j*256 + tid)*8] = sk[j];
            *(f16x8*)&vw[(j*256 + tid)*8] = sv[j];
        }
        __syncthreads();
    }

    // epilogue: O/l + qv -> ao (f16)
    float inv_l[4];
#pragma unroll
    for (int rr = 0; rr < 4; ++rr) inv_l[rr] = 1.f / o_l[rr];
#pragma unroll
    for (int rr = 0; rr < 4; ++rr) {
        size_t grow = ((size_t)b*SEQ + qt*64 + w*16 + qd*4 + rr) * DIM;
#pragma unroll
        for (int nt = 0; nt < 32; ++nt) {
            int col = nt*16 + mrow;
            float val = o[nt][rr] * inv_l[rr] + (float)qvh[grow + col];
            ao[grow + col] = (f16)val;
        }
    }
}

// ---------------------------------------------------------------------------
// Final linear: out[m,n] = sum_k ao[m,k]*Wf[n,k] + bf[n]  (f32 out)
// ---------------------------------------------------------------------------
__global__ __launch_bounds__(256) void final_gemm(
    const f16* __restrict__ ao, const float* __restrict__ Wf,
    const float* __restrict__ bf, float* __restrict__ out)
{
    __shared__ __attribute__((aligned(16))) f16 a_lds[128][40];
    __shared__ __attribute__((aligned(16))) f16 b_lds[128][40];

    const int m0 = blockIdx.y * 128, n0 = blockIdx.x * 128;
    const int tid = threadIdx.x, lane = tid & 63, wv = tid >> 6;
    const int wm = wv >> 1, wn = wv & 1, mrow = lane & 15, qd = lane >> 4;

    f32x4 acc[4][4];
#pragma unroll
    for (int mt = 0; mt < 4; ++mt)
#pragma unroll
        for (int nt = 0; nt < 4; ++nt) acc[mt][nt] = (f32x4){0.f,0.f,0.f,0.f};

    float bv[4];
#pragma unroll
    for (int nt = 0; nt < 4; ++nt) bv[nt] = bf[n0 + wn*64 + nt*16 + mrow];

    for (int k0 = 0; k0 < DIM; k0 += 32) {
        __syncthreads();
#pragma unroll
        for (int i = 0; i < 2; ++i) {
            int c = i*256 + tid;
            int row = c >> 2, c8 = c & 3;
            *(f16x8*)&a_lds[row][c8*8] =
                *(const f16x8*)(ao + (size_t)(m0+row)*DIM + k0 + c8*8);
        }
#pragma unroll
        for (int i = 0; i < 4; ++i) {
            int c = i*256 + tid;
            int row = c >> 3, c4 = c & 7;
            float4 v = *(const float4*)(Wf + (size_t)(n0+row)*DIM + k0 + c4*4);
            f16x4 hh = { (f16)v.x, (f16)v.y, (f16)v.z, (f16)v.w };
            *(f16x4*)&b_lds[row][c4*4] = hh;
        }
        __syncthreads();
        f16x8 af[4], bfr[4];
#pragma unroll
        for (int mt = 0; mt < 4; ++mt) af[mt]  = *(const f16x8*)&a_lds[wm*64 + mt*16 + mrow][qd*8];
#pragma unroll
        for (int nt = 0; nt < 4; ++nt) bfr[nt] = *(const f16x8*)&b_lds[wn*64 + nt*16 + mrow][qd*8];
#pragma unroll
        for (int mt = 0; mt < 4; ++mt)
#pragma unroll
            for (int nt = 0; nt < 4; ++nt)
                acc[mt][nt] = __builtin_amdgcn_mfma_f32_16x16x32_f16(af[mt], bfr[nt], acc[mt][nt], 0,0,0);
    }
#pragma unroll
    for (int mt = 0; mt < 4; ++mt)
#pragma unroll
        for (int r = 0; r < 4; ++r) {
            size_t grow = (size_t)(m0 + wm*64 + mt*16 + qd*4 + r) * DIM;
#pragma unroll
            for (int nt = 0; nt < 4; ++nt) {
                int col = n0 + wn*64 + nt*16 + mrow;
                out[grow + col] = acc[mt][nt][r] + bv[nt];
            }
        }
}

// ---------------------------------------------------------------------------
extern "C" void kernel_launch(void* const* d_in, const int* in_sizes, int n_in,
                              void* d_out, int out_size, void* d_ws, size_t ws_size,
                              hipStream_t stream)
{
    const float* x   = (const float*)d_in[0];
    const float* y   = (const float*)d_in[1];
    const float* Wq  = (const float*)d_in[2];
    const float* bq  = (const float*)d_in[3];
    const float* Wqv = (const float*)d_in[4];
    const float* bqv = (const float*)d_in[5];
    const float* Wk  = (const float*)d_in[6];
    const float* bk  = (const float*)d_in[7];
    const float* Wkv = (const float*)d_in[8];
    const float* bkv = (const float*)d_in[9];
    const float* Wf  = (const float*)d_in[10];
    const float* bf  = (const float*)d_in[11];
    float* out = (float*)d_out;

    f16* qh  = (f16*)d_ws;       // NEL f16 each; 84 MB total
    f16* qvh = qh  + NEL;
    f16* kS  = qvh + NEL;
    f16* vS  = kS  + NEL;
    f16* aob = vS  + NEL;

    proj_gemm<<<dim3(4, 128, 4), 256, 0, stream>>>(
        x, y, Wq, bq, Wqv, bqv, Wk, bk, Wkv, bkv, qh, qvh, kS, vS);
    attn_kernel<<<dim3(256), 256, 0, stream>>>(qh, kS, vS, qvh, aob);
    final_gemm<<<dim3(4, 128), 256, 0, stream>>>(aob, Wf, bf, out);
}